// Round 8
// baseline (12.943 us; speedup 1.0000x reference)
//
#include <hip/hip_runtime.h>
#include <math.h>

#define N_NODES 2048
#define N_RELS  16
#define N_FEAT  256
#define N_JOBS  17               // 16 relation dots + 1 outer_weight dot
#define THREADS 256

typedef int   v4i __attribute__((ext_vector_type(4)));
typedef float v4f __attribute__((ext_vector_type(4)));

__device__ __forceinline__ float sigmoidf_fast(float z) {
    return 1.0f / (1.0f + __expf(-z));
}

// Kernel 1 (R7-proven): one 64-lane wave per node, 512 blocks. x row loaded
// once; 17 independent dot chains fully unrolled; interleaved butterfly
// reduces (no serial dependence between jobs).
__global__ void __launch_bounds__(THREADS)
precompute_kernel(const float* __restrict__ x,
                  const float* __restrict__ relations,
                  const float* __restrict__ outer_weight,
                  float* __restrict__ A,   // [N_RELS][N_NODES]
                  float* __restrict__ B)   // [N_NODES]
{
    const int t    = blockIdx.x * blockDim.x + threadIdx.x;
    const int n    = t >> 6;   // wave id == node id; grid sized exactly
    const int lane = t & 63;

    const float4 xv = reinterpret_cast<const float4*>(x + n * N_FEAT)[lane];

    float acc[N_JOBS];
    #pragma unroll
    for (int j = 0; j < N_JOBS; ++j) {
        const float* rb = (j < N_RELS) ? (relations + j * N_FEAT)
                                       : outer_weight;
        const float4 rv = reinterpret_cast<const float4*>(rb)[lane];
        acc[j] = xv.x * rv.x + xv.y * rv.y + xv.z * rv.z + xv.w * rv.w;
    }
    #pragma unroll
    for (int off = 32; off > 0; off >>= 1) {
        #pragma unroll
        for (int j = 0; j < N_JOBS; ++j)
            acc[j] += __shfl_xor(acc[j], off, 64);
    }
    if (lane == 0) {
        #pragma unroll
        for (int j = 0; j < N_RELS; ++j)
            A[j * N_NODES + n] = acc[j];
        B[n] = acc[N_RELS];
    }
}

// Kernel 2: out[e] = sigmoid(A[rel[e]][src[e]] * B[dst[e]]), 4 edges/thread.
// int4 nontemporal index loads (16B/lane), 8 independent gathers in flight,
// float4 nontemporal store. 256 blocks.
__global__ void __launch_bounds__(THREADS)
edge_kernel(const int* __restrict__ src,
            const int* __restrict__ rel,
            const int* __restrict__ dst,
            const float* __restrict__ A,
            const float* __restrict__ B,
            float* __restrict__ out,
            int E)
{
    const int t  = blockIdx.x * blockDim.x + threadIdx.x;
    const int e4 = t * 4;
    if (e4 + 3 < E) {
        const v4i s = __builtin_nontemporal_load(
            reinterpret_cast<const v4i*>(src + e4));
        const v4i r = __builtin_nontemporal_load(
            reinterpret_cast<const v4i*>(rel + e4));
        const v4i d = __builtin_nontemporal_load(
            reinterpret_cast<const v4i*>(dst + e4));
        const float a0 = A[r.x * N_NODES + s.x];
        const float a1 = A[r.y * N_NODES + s.y];
        const float a2 = A[r.z * N_NODES + s.z];
        const float a3 = A[r.w * N_NODES + s.w];
        const float b0 = B[d.x];
        const float b1 = B[d.y];
        const float b2 = B[d.z];
        const float b3 = B[d.w];
        v4f o;
        o.x = sigmoidf_fast(a0 * b0);
        o.y = sigmoidf_fast(a1 * b1);
        o.z = sigmoidf_fast(a2 * b2);
        o.w = sigmoidf_fast(a3 * b3);
        __builtin_nontemporal_store(o, reinterpret_cast<v4f*>(out + e4));
    } else if (e4 < E) {
        for (int e = e4; e < E; ++e)
            out[e] = sigmoidf_fast(A[rel[e] * N_NODES + src[e]] * B[dst[e]]);
    }
}

extern "C" void kernel_launch(void* const* d_in, const int* in_sizes, int n_in,
                              void* d_out, int out_size, void* d_ws, size_t ws_size,
                              hipStream_t stream) {
    const float* x            = (const float*)d_in[0];
    const float* relations    = (const float*)d_in[1];
    const float* outer_weight = (const float*)d_in[2];
    const int*   edge_index   = (const int*)d_in[3];

    const int E = in_sizes[3] / 3;  // edge_index is [3, E]: rows src, rel, dst
    const int* src = edge_index;
    const int* rel = edge_index + E;
    const int* dst = edge_index + 2 * E;

    float* A = (float*)d_ws;             // 16*2048 floats = 128 KB
    float* B = A + N_RELS * N_NODES;     // 2048 floats = 8 KB

    const int pre_blocks = (N_NODES * 64) / THREADS;   // 512 blocks
    precompute_kernel<<<pre_blocks, THREADS, 0, stream>>>(
        x, relations, outer_weight, A, B);

    const int work = (E + 3) / 4;
    const int edge_blocks = (work + THREADS - 1) / THREADS;  // 256 blocks
    edge_kernel<<<edge_blocks, THREADS, 0, stream>>>(
        src, rel, dst, A, B, (float*)d_out, E);
}